// Round 10
// baseline (210.845 us; speedup 1.0000x reference)
//
#include <hip/hip_runtime.h>
#include <hip/hip_bf16.h>

#define BB 4
#define CC 256
#define NN 16384

typedef __hip_bfloat16 bf16;
typedef __attribute__((ext_vector_type(8))) short short8;
typedef __attribute__((ext_vector_type(4))) short s16x4;
typedef __attribute__((ext_vector_type(4))) float f32x4;

__device__ __forceinline__ float b2f(unsigned short u) {
  union { unsigned int i; float f; } x; x.i = ((unsigned int)u) << 16; return x.f;
}
__device__ __forceinline__ short f2bs(float v) {
  bf16 h = __float2bfloat16(v);
  return *reinterpret_cast<short*>(&h);
}
__device__ __forceinline__ f32x4 mfma16(short8 a, short8 b, f32x4 c) {
  return __builtin_amdgcn_mfma_f32_16x16x32_bf16(a, b, c, 0, 0, 0);
}

// stage x[b, 0..255, n0..n0+127] f32 -> LDS xs[n][j] bf16, XOR-swizzled 16B chunks.
// 512 threads: n = t&127 (lane-coalesced), j-quarter = t>>7; 8 iters x 8 j each.
__device__ __forceinline__ void stage_x_T(const float* __restrict__ xsrc, char* xb_lds, int t) {
  int sn = t & 127;
  int jh = t >> 7;  // 0..3
#pragma unroll
  for (int i = 0; i < 8; ++i) {
    int j0 = (jh + 4 * i) * 8;
    float f[8];
#pragma unroll
    for (int jc = 0; jc < 8; ++jc) f[jc] = xsrc[(size_t)(j0 + jc) * NN + sn];
    short8 pk;
#pragma unroll
    for (int jc = 0; jc < 8; ++jc) pk[jc] = f2bs(f[jc]);
    *(short8*)(xb_lds + sn * 512 + ((j0 * 2) ^ ((sn & 7) << 4))) = pk;
  }
}

// ---------------- prep: reorder/convert weights, BN constants, zero KVD + PART ----------------
__global__ __launch_bounds__(256) void prep_kernel(
    const float* __restrict__ Wqkv, const float* __restrict__ Wproj,
    const float* __restrict__ g, const float* __restrict__ bta,
    const float* __restrict__ mu, const float* __restrict__ var,
    bf16* __restrict__ Wq, bf16* __restrict__ Wkv, bf16* __restrict__ Wp,
    float* __restrict__ bns, float* __restrict__ KVD, float* __restrict__ PART) {
  int i = blockIdx.x * 256 + threadIdx.x;
  if (i < 4 * BB * 65536) PART[i] = 0.f;  // 4-way-split kv-state accumulators
  if (i < 1024) KVD[i] = 0.f;
  if (i < 768 * 256) {
    int o = i >> 8, c8 = i & 255;
    int c = o / 3, s = o - 3 * c;
    bf16 bv = __float2bfloat16(Wqkv[i]);
    if (s == 0) Wq[c * 256 + c8] = bv;
    else if (s == 1) Wkv[c * 256 + c8] = bv;
    else Wkv[(256 + c) * 256 + c8] = bv;
  }
  int j = i - 768 * 256;
  if (j >= 0 && j < 256 * 256) Wp[j] = __float2bfloat16(Wproj[j]);
  int k = i - (768 * 256 + 256 * 256);
  if (k >= 0 && k < 256) {
    float sc = g[k] * rsqrtf(var[k] + 1e-5f);
    bns[k] = sc;
    bns[256 + k] = bta[k] - mu[k] * sc;
  }
}

// ---------------- kvg2: fused k/v + kv-state. 256-n chunk per block, k/v stay on-chip ----------------
__global__ __launch_bounds__(512, 2) void kvg2_kernel(
    const float* __restrict__ X, const bf16* __restrict__ Wkv,
    float* __restrict__ PART, float* __restrict__ KVD) {
  __shared__ bf16 xs[64 * 256];    // 32 KB, rows 512B (j-dim), chunk ^= (n&7)
  __shared__ bf16 kbuf[256 * 64];  // 32 KB, rows 128B (n-dim), chunk ^= (c&7)
  __shared__ bf16 vbuf[256 * 64];  // 32 KB
  int b = blockIdx.y;
  int n0 = blockIdx.x * 256;
  int t = threadIdx.x, w = t >> 6, l = t & 63, lr = l & 15, lk = l >> 4;
  int wc = w & 3, wj = w >> 2;
  char* xb = (char*)xs;
  char* kb = (char*)kbuf;
  char* vb = (char*)vbuf;
  f32x4 kv[4][8] = {};  // persistent: 64c x 128j per wave
  const float* xsrc0 = X + (size_t)b * CC * NN + n0;

  for (int st = 0; st < 4; ++st) {
    __syncthreads();  // prev kv-GEMM done (kbuf/vbuf free), prev xs readers done
    // ---- stage 64-n subtile: n = t&63, j-eighth = t>>6 ----
    {
      const float* xsrc = xsrc0 + st * 64;
      int sn = t & 63, jh = t >> 6;  // jh 0..7
#pragma unroll
      for (int i = 0; i < 4; ++i) {
        int j0 = (jh + 8 * i) * 8;
        short8 pk;
#pragma unroll
        for (int jc = 0; jc < 8; ++jc) pk[jc] = f2bs(xsrc[(size_t)(j0 + jc) * NN + sn]);
        *(short8*)(xb + sn * 512 + ((j0 * 2) ^ ((sn & 7) << 4))) = pk;
      }
    }
    __syncthreads();
    // ---- k then v: A=xs rows n (64), B=Wkv rows c (w*32 slice); acc 64n x 32c ----
#pragma unroll
    for (int ph = 0; ph < 2; ++ph) {
      f32x4 acc[4][2] = {};
      for (int k0 = 0; k0 < 256; k0 += 32) {
        short8 a[4];
#pragma unroll
        for (int mt = 0; mt < 4; ++mt) {
          int rn = mt * 16 + lr;
          a[mt] = *(const short8*)(xb + rn * 512 + ((k0 * 2 + lk * 16) ^ ((rn & 7) << 4)));
        }
#pragma unroll
        for (int nt = 0; nt < 2; ++nt) {
          short8 bw = *(const short8*)(Wkv + (size_t)(ph * 256 + w * 32 + nt * 16 + lr) * CC + k0 + lk * 8);
#pragma unroll
          for (int mt = 0; mt < 4; ++mt) acc[mt][nt] = mfma16(a[mt], bw, acc[mt][nt]);
        }
      }
      char* obuf = (ph == 0) ? kb : vb;
      if (ph == 0) {
        // relu + kvd column sums (lanes sharing c: lr fixed, lk varies -> xor 16,32)
#pragma unroll
        for (int nt = 0; nt < 2; ++nt) {
          float s = 0.f;
#pragma unroll
          for (int mt = 0; mt < 4; ++mt)
#pragma unroll
            for (int e = 0; e < 4; ++e) {
              float v = acc[mt][nt][e];
              v = v > 0.f ? v : 0.f;
              acc[mt][nt][e] = v;
              s += v;
            }
          s += __shfl_xor(s, 16);
          s += __shfl_xor(s, 32);
          if (lk == 0) atomicAdd(&KVD[b * 256 + w * 32 + nt * 16 + lr], s);
        }
      }
      // writeback to [c][n] rows 128B, 4 consecutive n -> b64, chunk ^= (c&7)
#pragma unroll
      for (int mt = 0; mt < 4; ++mt)
#pragma unroll
        for (int nt = 0; nt < 2; ++nt) {
          int c = w * 32 + nt * 16 + lr;
          int nn0 = mt * 16 + 4 * lk;
          int chunk = nn0 >> 3;
          s16x4 pk;
#pragma unroll
          for (int e = 0; e < 4; ++e) pk[e] = f2bs(acc[mt][nt][e]);
          *(s16x4*)(obuf + c * 128 + ((chunk ^ (c & 7)) * 16) + (nn0 & 7) * 2) = pk;
        }
    }
    __syncthreads();
    // ---- kv-GEMM: A=kbuf rows c (wc*64), B=vbuf rows j (wj*128), K=64 n ----
    for (int kk = 0; kk < 64; kk += 32) {
      int chunk = (kk >> 3) + lk;
      short8 a[4];
#pragma unroll
      for (int mt = 0; mt < 4; ++mt) {
        int c = wc * 64 + mt * 16 + lr;
        a[mt] = *(const short8*)(kb + c * 128 + ((chunk ^ (c & 7)) * 16));
      }
#pragma unroll
      for (int nt = 0; nt < 8; ++nt) {
        int j = wj * 128 + nt * 16 + lr;
        short8 bb = *(const short8*)(vb + j * 128 + ((chunk ^ (j & 7)) * 16));
#pragma unroll
        for (int mt = 0; mt < 4; ++mt) kv[mt][nt] = mfma16(a[mt], bb, kv[mt][nt]);
      }
    }
  }
  // ---- accumulate into 4-way split PART (f32, L2-resident) ----
  float* P = PART + (((size_t)((blockIdx.x & 3) * BB + b)) << 16);
#pragma unroll
  for (int mt = 0; mt < 4; ++mt)
#pragma unroll
    for (int nt = 0; nt < 8; ++nt)
#pragma unroll
      for (int e = 0; e < 4; ++e) {
        int c = wc * 64 + mt * 16 + 4 * lk + e;
        int j = wj * 128 + nt * 16 + lr;
        atomicAdd(&P[c * 256 + j], kv[mt][nt][e]);
      }
}

// ---------------- reduce 4 PART copies -> KVJ bf16 [b][c][j] ----------------
__global__ __launch_bounds__(256) void kvred_kernel(const float* __restrict__ PART, bf16* __restrict__ KVJ) {
  int idx = blockIdx.x * 256 + threadIdx.x;  // BB*65536
  int b = idx >> 16, rem = idx & 65535;
  float s = 0.f;
#pragma unroll
  for (int cp = 0; cp < 4; ++cp) s += PART[(((size_t)(cp * BB + b)) << 16) + rem];
  KVJ[idx] = __float2bfloat16(s);
}

// ---------------- mker: M[o][c] = scale[o] * sum_j Wp[o,j] * KVJ[c,j] ----------------
__global__ __launch_bounds__(256) void mker_kernel(const bf16* __restrict__ Wp,
                                                   const bf16* __restrict__ KVJ,
                                                   const float* __restrict__ bns,
                                                   bf16* __restrict__ Mb) {
  int b = blockIdx.z;
  int o0 = blockIdx.x * 128, c0 = blockIdx.y * 128;
  int t = threadIdx.x, w = t >> 6, lr = t & 15, lk = (t & 63) >> 4;
  const bf16* A = Wp + (size_t)(o0 + w * 32) * 256;
  const bf16* Bp = KVJ + ((size_t)b << 16) + (size_t)c0 * 256;
  f32x4 acc[2][8] = {};
  for (int k0 = 0; k0 < 256; k0 += 32) {
    short8 a[2];
#pragma unroll
    for (int mt = 0; mt < 2; ++mt)
      a[mt] = *(const short8*)(A + (size_t)(mt * 16 + lr) * 256 + k0 + lk * 8);
#pragma unroll
    for (int nt = 0; nt < 8; ++nt) {
      short8 bb = *(const short8*)(Bp + (size_t)(nt * 16 + lr) * 256 + k0 + lk * 8);
#pragma unroll
      for (int mt = 0; mt < 2; ++mt) acc[mt][nt] = mfma16(a[mt], bb, acc[mt][nt]);
    }
  }
#pragma unroll
  for (int mt = 0; mt < 2; ++mt)
#pragma unroll
    for (int nt = 0; nt < 8; ++nt)
#pragma unroll
      for (int e = 0; e < 4; ++e) {
        int o = o0 + w * 32 + mt * 16 + 4 * lk + e;
        int c = c0 + nt * 16 + lr;
        Mb[((size_t)b << 16) + (size_t)o * 256 + c] = __float2bfloat16(acc[mt][nt][e] * bns[o]);
      }
}

// ---------------- g5: stage x, q in-kernel (b64 writeback), den, M-GEMM; 8 waves ----------------
__global__ __launch_bounds__(512) void g5_kernel(const float* __restrict__ X,
                                                 const bf16* __restrict__ Wq,
                                                 const bf16* __restrict__ Mb,
                                                 const float* __restrict__ KVD,
                                                 const float* __restrict__ bns,
                                                 float* __restrict__ Y) {
  __shared__ bf16 qs[128 * 256];  // 64 KB: holds x-tile, then overwritten with q
  __shared__ float recip_s[128];
  __shared__ float shift_s[256];
  int b = blockIdx.y;
  int n0 = blockIdx.x * 128;
  int t = threadIdx.x, w = t >> 6, l = t & 63, lr = l & 15, lk = l >> 4;
  if (t < 256) shift_s[t] = bns[256 + t];
  stage_x_T(X + (size_t)b * CC * NN + n0, (char*)qs, t);
  __syncthreads();
  char* qb = (char*)qs;

  // ---- q-GEMM: rows=c (A=Wq w-slice 32c), cols=n (B=xs); acc[2][8] = 32c x 128n ----
  {
    f32x4 qa[2][8] = {};
    for (int k0 = 0; k0 < 256; k0 += 32) {
      short8 a[2];
#pragma unroll
      for (int mt = 0; mt < 2; ++mt)
        a[mt] = *(const short8*)(Wq + (size_t)(w * 32 + mt * 16 + lr) * CC + k0 + lk * 8);
#pragma unroll
      for (int nt = 0; nt < 8; ++nt) {
        int rn = nt * 16 + lr;
        short8 bb = *(const short8*)(qb + rn * 512 + ((k0 * 2 + lk * 16) ^ ((rn & 7) << 4)));
#pragma unroll
        for (int mt = 0; mt < 2; ++mt) qa[mt][nt] = mfma16(a[mt], bb, qa[mt][nt]);
      }
    }
    __syncthreads();  // all waves done reading x-tile
#pragma unroll
    for (int mt = 0; mt < 2; ++mt)
#pragma unroll
      for (int nt = 0; nt < 8; ++nt) {
        int n = nt * 16 + lr;
        int c0 = w * 32 + mt * 16 + 4 * lk;
        s16x4 pk;
#pragma unroll
        for (int e = 0; e < 4; ++e) {
          float v = qa[mt][nt][e];
          pk[e] = f2bs(v > 0.f ? v : 0.f);
        }
        *(s16x4*)(qb + n * 512 + ((c0 * 2) ^ ((n & 7) << 4))) = pk;
      }
  }
  __syncthreads();

  // ---- denominator: 4 threads per n-row, 8 chunks each ----
  {
    int row = t >> 2, qtr = t & 3;
    const float* kd = KVD + b * 256;
    float s = 0.f;
#pragma unroll
    for (int jj = 0; jj < 8; ++jj) {
      int chunk = qtr * 8 + jj;
      short8 v = *(const short8*)(qb + row * 512 + ((chunk * 16) ^ ((row & 7) << 4)));
      const float* kp = kd + chunk * 8;
#pragma unroll
      for (int e = 0; e < 8; ++e) s += b2f((unsigned short)v[e]) * kp[e];
    }
    s += __shfl_xor(s, 1);
    s += __shfl_xor(s, 2);
    if (qtr == 0) recip_s[row] = 1.f / (s + 1e-5f);
  }
  __syncthreads();

  // ---- M-GEMM: A = q (LDS, rows n), B = Mb w-slice (32 o rows); packed dwordx4 stores ----
  f32x4 acc[8][2] = {};
  for (int k0 = 0; k0 < 256; k0 += 32) {
    short8 a[8];
#pragma unroll
    for (int mt = 0; mt < 8; ++mt) {
      int rn = mt * 16 + lr;
      a[mt] = *(const short8*)(qb + rn * 512 + ((k0 * 2 + lk * 16) ^ ((rn & 7) << 4)));
    }
#pragma unroll
    for (int nt = 0; nt < 2; ++nt) {
      short8 bw = *(const short8*)(Mb + ((size_t)b << 16) + (size_t)(w * 32 + nt * 16 + lr) * 256 + k0 + lk * 8);
#pragma unroll
      for (int mt = 0; mt < 8; ++mt) acc[mt][nt] = mfma16(a[mt], bw, acc[mt][nt]);
    }
  }
  float* Yb = Y + (size_t)b * CC * NN;
#pragma unroll
  for (int mt = 0; mt < 8; ++mt)
#pragma unroll
    for (int nt = 0; nt < 2; ++nt) {
      int o = w * 32 + nt * 16 + lr;
      int nb = mt * 16 + 4 * lk;
      f32x4 out;
#pragma unroll
      for (int e = 0; e < 4; ++e) out[e] = acc[mt][nt][e] * recip_s[nb + e] + shift_s[o];
      *(f32x4*)(Yb + (size_t)o * NN + n0 + nb) = out;
    }
}

extern "C" void kernel_launch(void* const* d_in, const int* in_sizes, int n_in,
                              void* d_out, int out_size, void* d_ws, size_t ws_size,
                              hipStream_t stream) {
  const float* x = (const float*)d_in[0];
  const float* Wqkv = (const float*)d_in[1];
  const float* Wproj = (const float*)d_in[2];
  const float* g = (const float*)d_in[3];
  const float* bta = (const float*)d_in[4];
  const float* mu = (const float*)d_in[5];
  const float* var = (const float*)d_in[6];
  float* Y = (float*)d_out;

  char* ws = (char*)d_ws;
  size_t off = 0;
  auto alloc = [&](size_t bytes) -> void* {
    void* p = ws + off;
    off += (bytes + 255) & ~(size_t)255;
    return p;
  };
  float* PART = (float*)alloc((size_t)4 * BB * 65536 * 4);  // 4 MB: 4 copies x B x 256 x 256
  bf16* KVJ = (bf16*)alloc((size_t)BB * 65536 * 2);
  bf16* Mbuf = (bf16*)alloc((size_t)BB * 65536 * 2);
  float* KVD = (float*)alloc((size_t)BB * 256 * 4);
  bf16* Wq = (bf16*)alloc(256 * 256 * 2);
  bf16* Wkv = (bf16*)alloc(512 * 256 * 2);
  bf16* Wp = (bf16*)alloc(256 * 256 * 2);
  float* bns = (float*)alloc(512 * 4);

  prep_kernel<<<4096, 256, 0, stream>>>(Wqkv, Wproj, g, bta, mu, var, Wq, Wkv, Wp, bns, KVD, PART);
  kvg2_kernel<<<dim3(NN / 256, BB), 512, 0, stream>>>(x, Wkv, PART, KVD);
  kvred_kernel<<<BB * 65536 / 256, 256, 0, stream>>>(PART, KVJ);
  mker_kernel<<<dim3(2, 2, BB), 256, 0, stream>>>(Wp, KVJ, bns, Mbuf);
  g5_kernel<<<dim3(NN / 128, BB), 512, 0, stream>>>(x, Wq, Mbuf, KVD, bns, Y);
}

// Round 12
// 160.771 us; speedup vs baseline: 1.3115x; 1.3115x over previous
//
#include <hip/hip_runtime.h>
#include <hip/hip_bf16.h>
#include <hip/hip_cooperative_groups.h>

namespace cg = cooperative_groups;

#define BB 4
#define CC 256
#define NN 16384

typedef __hip_bfloat16 bf16;
typedef __attribute__((ext_vector_type(8))) short short8;
typedef __attribute__((ext_vector_type(4))) short s16x4;
typedef __attribute__((ext_vector_type(4))) float f32x4;

__device__ __forceinline__ float b2f(unsigned short u) {
  union { unsigned int i; float f; } x; x.i = ((unsigned int)u) << 16; return x.f;
}
__device__ __forceinline__ short f2bs(float v) {
  bf16 h = __float2bfloat16(v);
  return *reinterpret_cast<short*>(&h);
}
__device__ __forceinline__ f32x4 mfma16(short8 a, short8 b, f32x4 c) {
  return __builtin_amdgcn_mfma_f32_16x16x32_bf16(a, b, c, 0, 0, 0);
}

// stage x[b, 0..255, n0..n0+127] f32 -> LDS xs[n][j] bf16, XOR-swizzled 16B chunks.
// 512 threads: n = t&127 (lane-coalesced), j-quarter = t>>7; 8 iters x 8 j each.
__device__ __forceinline__ void stage_x_T(const float* __restrict__ xsrc, char* xb_lds, int t) {
  int sn = t & 127;
  int jh = t >> 7;  // 0..3
#pragma unroll
  for (int i = 0; i < 8; ++i) {
    int j0 = (jh + 4 * i) * 8;
    float f[8];
#pragma unroll
    for (int jc = 0; jc < 8; ++jc) f[jc] = xsrc[(size_t)(j0 + jc) * NN + sn];
    short8 pk;
#pragma unroll
    for (int jc = 0; jc < 8; ++jc) pk[jc] = f2bs(f[jc]);
    *(short8*)(xb_lds + sn * 512 + ((j0 * 2) ^ ((sn & 7) << 4))) = pk;
  }
}

// ---------------- prep: reorder/convert weights, BN constants, zero KVD ----------------
__global__ __launch_bounds__(256) void prep_kernel(
    const float* __restrict__ Wqkv, const float* __restrict__ Wproj,
    const float* __restrict__ g, const float* __restrict__ bta,
    const float* __restrict__ mu, const float* __restrict__ var,
    bf16* __restrict__ Wq, bf16* __restrict__ Wkv, bf16* __restrict__ Wp,
    float* __restrict__ bns, float* __restrict__ KVD) {
  int i = blockIdx.x * 256 + threadIdx.x;
  if (i < 1024) KVD[i] = 0.f;
  if (i < 768 * 256) {
    int o = i >> 8, c8 = i & 255;
    int c = o / 3, s = o - 3 * c;
    bf16 bv = __float2bfloat16(Wqkv[i]);
    if (s == 0) Wq[c * 256 + c8] = bv;
    else if (s == 1) Wkv[c * 256 + c8] = bv;
    else Wkv[(256 + c) * 256 + c8] = bv;
  }
  int j = i - 768 * 256;
  if (j >= 0 && j < 256 * 256) Wp[j] = __float2bfloat16(Wproj[j]);
  int k = i - (768 * 256 + 256 * 256);
  if (k >= 0 && k < 256) {
    float sc = g[k] * rsqrtf(var[k] + 1e-5f);
    bns[k] = sc;
    bns[256 + k] = bta[k] - mu[k] * sc;
  }
}

// ================= fused cooperative kernel (dynamic LDS: 64K tile + 512B recip + 1K shift) =================
__global__ __launch_bounds__(512, 4) void fused_kernel(
    const float* __restrict__ X, const bf16* __restrict__ Wq,
    const bf16* __restrict__ Wkv, const bf16* __restrict__ Wp,
    const float* __restrict__ bns, float* __restrict__ KVD,
    bf16* __restrict__ KB, bf16* __restrict__ VB, float* __restrict__ PART,
    bf16* __restrict__ KVJ, bf16* __restrict__ Mb, float* __restrict__ Y) {
  cg::grid_group grid = cg::this_grid();
  extern __shared__ char smem[];
  char* xb = smem;                                  // 64 KB: x tile, later q tile
  float* recip_s = (float*)(smem + 65536);          // 512 B
  float* shift_s = (float*)(smem + 66048);          // 1 KB
  int bid = blockIdx.x;
  int t = threadIdx.x, w = t >> 6, l = t & 63, lr = l & 15, lk = l >> 4;
  if (t < 256) shift_s[t] = bns[256 + t];
  int b = bid >> 7, n0 = (bid & 127) * 128;

  // ===== phase A: stage x; k,v -> global (+kvd); q -> back into LDS =====
  stage_x_T(X + (size_t)b * CC * NN + n0, xb, t);
  __syncthreads();
#pragma unroll
  for (int ph = 0; ph < 2; ++ph) {
    f32x4 acc[2][8] = {};
    for (int k0 = 0; k0 < 256; k0 += 32) {
      short8 a[2];
#pragma unroll
      for (int mt = 0; mt < 2; ++mt)
        a[mt] = *(const short8*)(Wkv + (size_t)(ph * 256 + w * 32 + mt * 16 + lr) * CC + k0 + lk * 8);
#pragma unroll
      for (int nt = 0; nt < 8; ++nt) {
        int rn = nt * 16 + lr;
        short8 bb = *(const short8*)(xb + rn * 512 + ((k0 * 2 + lk * 16) ^ ((rn & 7) << 4)));
#pragma unroll
        for (int mt = 0; mt < 2; ++mt) acc[mt][nt] = mfma16(a[mt], bb, acc[mt][nt]);
      }
    }
    bf16* Out = (ph == 0 ? KB : VB) + (size_t)b * CC * NN;
    if (ph == 0) {
#pragma unroll
      for (int mt = 0; mt < 2; ++mt)
#pragma unroll
        for (int e = 0; e < 4; ++e) {
          float s = 0.f;
#pragma unroll
          for (int nt = 0; nt < 8; ++nt) {
            float v = acc[mt][nt][e];
            v = v > 0.f ? v : 0.f;
            acc[mt][nt][e] = v;
            s += v;
          }
          s += __shfl_xor(s, 1);
          s += __shfl_xor(s, 2);
          s += __shfl_xor(s, 4);
          s += __shfl_xor(s, 8);
          int c = w * 32 + mt * 16 + 4 * lk + e;
          if (lr == 0) atomicAdd(&KVD[b * 256 + c], s);
        }
    }
#pragma unroll
    for (int mt = 0; mt < 2; ++mt)
#pragma unroll
      for (int nt = 0; nt < 8; ++nt)
#pragma unroll
        for (int e = 0; e < 4; ++e) {
          int c = w * 32 + mt * 16 + 4 * lk + e;
          int n = nt * 16 + lr;
          Out[(size_t)c * NN + n0 + n] = __float2bfloat16(acc[mt][nt][e]);
        }
  }
  {
    f32x4 qa[2][8] = {};
    for (int k0 = 0; k0 < 256; k0 += 32) {
      short8 a[2];
#pragma unroll
      for (int mt = 0; mt < 2; ++mt)
        a[mt] = *(const short8*)(Wq + (size_t)(w * 32 + mt * 16 + lr) * CC + k0 + lk * 8);
#pragma unroll
      for (int nt = 0; nt < 8; ++nt) {
        int rn = nt * 16 + lr;
        short8 bb = *(const short8*)(xb + rn * 512 + ((k0 * 2 + lk * 16) ^ ((rn & 7) << 4)));
#pragma unroll
        for (int mt = 0; mt < 2; ++mt) qa[mt][nt] = mfma16(a[mt], bb, qa[mt][nt]);
      }
    }
    __syncthreads();  // all waves done reading the x tile
#pragma unroll
    for (int mt = 0; mt < 2; ++mt)
#pragma unroll
      for (int nt = 0; nt < 8; ++nt) {
        int n = nt * 16 + lr;
        int c0 = w * 32 + mt * 16 + 4 * lk;
        s16x4 pk;
#pragma unroll
        for (int e = 0; e < 4; ++e) {
          float v = qa[mt][nt][e];
          pk[e] = f2bs(v > 0.f ? v : 0.f);
        }
        *(s16x4*)(xb + n * 512 + ((c0 * 2) ^ ((n & 7) << 4))) = pk;
      }
  }
  __syncthreads();
  __threadfence();
  grid.sync();

  // ===== B1: g2 split-K, 128 active blocks, private PART slices =====
  if (bid < 128) {
    int gb = bid >> 5, sub = bid & 31;
    int chunk = sub >> 1, tj = (sub & 1) * 128;
    int nb = chunk * 1024;
    const bf16* A = KB + ((size_t)gb * CC + w * 32) * NN + nb;
    const bf16* Bp = VB + ((size_t)gb * CC + tj) * NN + nb;
    f32x4 acc[2][8] = {};
    for (int k0 = 0; k0 < 1024; k0 += 32) {
      short8 a[2];
#pragma unroll
      for (int mt = 0; mt < 2; ++mt)
        a[mt] = *(const short8*)(A + (size_t)(mt * 16 + lr) * NN + k0 + lk * 8);
#pragma unroll
      for (int nt = 0; nt < 8; ++nt) {
        short8 bb = *(const short8*)(Bp + (size_t)(nt * 16 + lr) * NN + k0 + lk * 8);
#pragma unroll
        for (int mt = 0; mt < 2; ++mt) acc[mt][nt] = mfma16(a[mt], bb, acc[mt][nt]);
      }
    }
    float* P = PART + (((size_t)(gb * 16 + chunk)) << 16);
#pragma unroll
    for (int mt = 0; mt < 2; ++mt)
#pragma unroll
      for (int nt = 0; nt < 8; ++nt)
#pragma unroll
        for (int e = 0; e < 4; ++e) {
          int c = w * 32 + mt * 16 + 4 * lk + e;
          int j = tj + nt * 16 + lr;
          P[(size_t)c * 256 + j] = acc[mt][nt][e];
        }
  }
  __threadfence();
  grid.sync();

  // ===== B2: kvred =====
  {
    int idx = bid * 512 + t;
    int gb = idx >> 16, rem = idx & 65535;
    float s = 0.f;
#pragma unroll
    for (int ch = 0; ch < 16; ++ch) s += PART[(((size_t)(gb * 16 + ch)) << 16) + rem];
    KVJ[idx] = __float2bfloat16(s);
  }
  __threadfence();
  grid.sync();

  // ===== B3: mker (16 blocks) =====
  if (bid < 16) {
    int gb = bid >> 2, qd = bid & 3;
    int o0 = (qd & 1) * 128, c0 = (qd >> 1) * 128;
    const bf16* A = Wp + (size_t)(o0 + w * 16) * 256;
    const bf16* Bp = KVJ + ((size_t)gb << 16) + (size_t)c0 * 256;
    f32x4 acc[8] = {};
    for (int k0 = 0; k0 < 256; k0 += 32) {
      short8 a = *(const short8*)(A + (size_t)lr * 256 + k0 + lk * 8);
#pragma unroll
      for (int nt = 0; nt < 8; ++nt) {
        short8 bb = *(const short8*)(Bp + (size_t)(nt * 16 + lr) * 256 + k0 + lk * 8);
        acc[nt] = mfma16(a, bb, acc[nt]);
      }
    }
#pragma unroll
    for (int nt = 0; nt < 8; ++nt)
#pragma unroll
      for (int e = 0; e < 4; ++e) {
        int o = o0 + w * 16 + 4 * lk + e;
        int c = c0 + nt * 16 + lr;
        Mb[((size_t)gb << 16) + (size_t)o * 256 + c] = __float2bfloat16(acc[nt][e] * bns[o]);
      }
  }
  __threadfence();
  grid.sync();

  // ===== C: denominator + M-GEMM from resident LDS q tile =====
  {
    int row = t >> 2, qtr = t & 3;
    const float* kd = KVD + b * 256;
    float s = 0.f;
#pragma unroll
    for (int jj = 0; jj < 8; ++jj) {
      int chunk = qtr * 8 + jj;
      short8 v = *(const short8*)(xb + row * 512 + ((chunk * 16) ^ ((row & 7) << 4)));
      const float* kp = kd + chunk * 8;
#pragma unroll
      for (int e = 0; e < 8; ++e) s += b2f((unsigned short)v[e]) * kp[e];
    }
    s += __shfl_xor(s, 1);
    s += __shfl_xor(s, 2);
    if (qtr == 0) recip_s[row] = 1.f / (s + 1e-5f);
  }
  __syncthreads();
  {
    f32x4 acc[8][2] = {};
    for (int k0 = 0; k0 < 256; k0 += 32) {
      short8 a[8];
#pragma unroll
      for (int mt = 0; mt < 8; ++mt) {
        int rn = mt * 16 + lr;
        a[mt] = *(const short8*)(xb + rn * 512 + ((k0 * 2 + lk * 16) ^ ((rn & 7) << 4)));
      }
#pragma unroll
      for (int nt = 0; nt < 2; ++nt) {
        short8 bw = *(const short8*)(Mb + ((size_t)b << 16) + (size_t)(w * 32 + nt * 16 + lr) * 256 + k0 + lk * 8);
#pragma unroll
        for (int mt = 0; mt < 8; ++mt) acc[mt][nt] = mfma16(a[mt], bw, acc[mt][nt]);
      }
    }
    float* Yb = Y + (size_t)b * CC * NN;
#pragma unroll
    for (int mt = 0; mt < 8; ++mt)
#pragma unroll
      for (int nt = 0; nt < 2; ++nt) {
        int o = w * 32 + nt * 16 + lr;
        int nb = mt * 16 + 4 * lk;
        f32x4 out;
#pragma unroll
        for (int e = 0; e < 4; ++e) out[e] = acc[mt][nt][e] * recip_s[nb + e] + shift_s[o];
        *(f32x4*)(Yb + (size_t)o * NN + n0 + nb) = out;
      }
  }
}

// ================= fallback path (r9 kernels, proven 163 us) =================
__global__ __launch_bounds__(512) void kv_kernel(
    const float* __restrict__ X, const bf16* __restrict__ Wkv,
    bf16* __restrict__ KB, bf16* __restrict__ VB, float* __restrict__ KVD) {
  __shared__ bf16 xs[128 * 256];
  int b = blockIdx.y;
  int n0 = blockIdx.x * 128;
  int t = threadIdx.x, w = t >> 6, l = t & 63, lr = l & 15, lk = l >> 4;
  stage_x_T(X + (size_t)b * CC * NN + n0, (char*)xs, t);
  __syncthreads();
  const char* xb = (const char*)xs;
#pragma unroll
  for (int ph = 0; ph < 2; ++ph) {
    f32x4 acc[2][8] = {};
    for (int k0 = 0; k0 < 256; k0 += 32) {
      short8 a[2];
#pragma unroll
      for (int mt = 0; mt < 2; ++mt)
        a[mt] = *(const short8*)(Wkv + (size_t)(ph * 256 + w * 32 + mt * 16 + lr) * CC + k0 + lk * 8);
#pragma unroll
      for (int nt = 0; nt < 8; ++nt) {
        int rn = nt * 16 + lr;
        short8 bb = *(const short8*)(xb + rn * 512 + ((k0 * 2 + lk * 16) ^ ((rn & 7) << 4)));
#pragma unroll
        for (int mt = 0; mt < 2; ++mt) acc[mt][nt] = mfma16(a[mt], bb, acc[mt][nt]);
      }
    }
    bf16* Out = (ph == 0 ? KB : VB) + (size_t)b * CC * NN;
    if (ph == 0) {
#pragma unroll
      for (int mt = 0; mt < 2; ++mt)
#pragma unroll
        for (int e = 0; e < 4; ++e) {
          float s = 0.f;
#pragma unroll
          for (int nt = 0; nt < 8; ++nt) {
            float v = acc[mt][nt][e];
            v = v > 0.f ? v : 0.f;
            acc[mt][nt][e] = v;
            s += v;
          }
          s += __shfl_xor(s, 1);
          s += __shfl_xor(s, 2);
          s += __shfl_xor(s, 4);
          s += __shfl_xor(s, 8);
          int c = w * 32 + mt * 16 + 4 * lk + e;
          if (lr == 0) atomicAdd(&KVD[b * 256 + c], s);
        }
    }
#pragma unroll
    for (int mt = 0; mt < 2; ++mt)
#pragma unroll
      for (int nt = 0; nt < 8; ++nt)
#pragma unroll
        for (int e = 0; e < 4; ++e) {
          int c = w * 32 + mt * 16 + 4 * lk + e;
          int n = nt * 16 + lr;
          Out[(size_t)c * NN + n0 + n] = __float2bfloat16(acc[mt][nt][e]);
        }
  }
}

__global__ __launch_bounds__(256) void g2_kernel(const bf16* __restrict__ KB,
                                                 const bf16* __restrict__ VB,
                                                 float* __restrict__ PART) {
  int b = blockIdx.z, chunk = blockIdx.y;
  int tc = (blockIdx.x & 1) * 128;
  int tj = (blockIdx.x >> 1) * 128;
  int nb = chunk * 1024;
  int t = threadIdx.x, w = t >> 6, lr = t & 15, lk = (t & 63) >> 4;
  const bf16* A = KB + ((size_t)b * CC + tc + w * 32) * NN + nb;
  const bf16* Bp = VB + ((size_t)b * CC + tj) * NN + nb;
  f32x4 acc[2][8] = {};
  for (int k0 = 0; k0 < 1024; k0 += 32) {
    short8 a[2];
#pragma unroll
    for (int mt = 0; mt < 2; ++mt)
      a[mt] = *(const short8*)(A + (size_t)(mt * 16 + lr) * NN + k0 + lk * 8);
#pragma unroll
    for (int nt = 0; nt < 8; ++nt) {
      short8 bb = *(const short8*)(Bp + (size_t)(nt * 16 + lr) * NN + k0 + lk * 8);
#pragma unroll
      for (int mt = 0; mt < 2; ++mt) acc[mt][nt] = mfma16(a[mt], bb, acc[mt][nt]);
    }
  }
  float* P = PART + (((size_t)(b * 16 + chunk)) << 16);
#pragma unroll
  for (int mt = 0; mt < 2; ++mt)
#pragma unroll
    for (int nt = 0; nt < 8; ++nt)
#pragma unroll
      for (int e = 0; e < 4; ++e) {
        int c = tc + w * 32 + mt * 16 + 4 * lk + e;
        int j = tj + nt * 16 + lr;
        P[(size_t)c * 256 + j] = acc[mt][nt][e];
      }
}

__global__ __launch_bounds__(256) void kvred_kernel(const float* __restrict__ PART, bf16* __restrict__ KVJ) {
  int idx = blockIdx.x * 256 + threadIdx.x;
  int b = idx >> 16, rem = idx & 65535;
  float s = 0.f;
#pragma unroll
  for (int ch = 0; ch < 16; ++ch) s += PART[(((size_t)(b * 16 + ch)) << 16) + rem];
  KVJ[idx] = __float2bfloat16(s);
}

__global__ __launch_bounds__(256) void mker_kernel(const bf16* __restrict__ Wp,
                                                   const bf16* __restrict__ KVJ,
                                                   const float* __restrict__ bns,
                                                   bf16* __restrict__ Mb) {
  int b = blockIdx.z;
  int o0 = blockIdx.x * 128, c0 = blockIdx.y * 128;
  int t = threadIdx.x, w = t >> 6, lr = t & 15, lk = (t & 63) >> 4;
  const bf16* A = Wp + (size_t)(o0 + w * 32) * 256;
  const bf16* Bp = KVJ + ((size_t)b << 16) + (size_t)c0 * 256;
  f32x4 acc[2][8] = {};
  for (int k0 = 0; k0 < 256; k0 += 32) {
    short8 a[2];
#pragma unroll
    for (int mt = 0; mt < 2; ++mt)
      a[mt] = *(const short8*)(A + (size_t)(mt * 16 + lr) * 256 + k0 + lk * 8);
#pragma unroll
    for (int nt = 0; nt < 8; ++nt) {
      short8 bb = *(const short8*)(Bp + (size_t)(nt * 16 + lr) * 256 + k0 + lk * 8);
#pragma unroll
      for (int mt = 0; mt < 2; ++mt) acc[mt][nt] = mfma16(a[mt], bb, acc[mt][nt]);
    }
  }
#pragma unroll
  for (int mt = 0; mt < 2; ++mt)
#pragma unroll
    for (int nt = 0; nt < 8; ++nt)
#pragma unroll
      for (int e = 0; e < 4; ++e) {
        int o = o0 + w * 32 + mt * 16 + 4 * lk + e;
        int c = c0 + nt * 16 + lr;
        Mb[((size_t)b << 16) + (size_t)o * 256 + c] = __float2bfloat16(acc[mt][nt][e] * bns[o]);
      }
}

__global__ __launch_bounds__(512) void g5_kernel(const float* __restrict__ X,
                                                 const bf16* __restrict__ Wq,
                                                 const bf16* __restrict__ Mb,
                                                 const float* __restrict__ KVD,
                                                 const float* __restrict__ bns,
                                                 float* __restrict__ Y) {
  __shared__ bf16 qs[128 * 256];
  __shared__ float recip_s[128];
  __shared__ float shift_s[256];
  int b = blockIdx.y;
  int n0 = blockIdx.x * 128;
  int t = threadIdx.x, w = t >> 6, l = t & 63, lr = l & 15, lk = l >> 4;
  if (t < 256) shift_s[t] = bns[256 + t];
  stage_x_T(X + (size_t)b * CC * NN + n0, (char*)qs, t);
  __syncthreads();
  char* qb = (char*)qs;
  {
    f32x4 qa[2][8] = {};
    for (int k0 = 0; k0 < 256; k0 += 32) {
      short8 a[2];
#pragma unroll
      for (int mt = 0; mt < 2; ++mt)
        a[mt] = *(const short8*)(Wq + (size_t)(w * 32 + mt * 16 + lr) * CC + k0 + lk * 8);
#pragma unroll
      for (int nt = 0; nt < 8; ++nt) {
        int rn = nt * 16 + lr;
        short8 bb = *(const short8*)(qb + rn * 512 + ((k0 * 2 + lk * 16) ^ ((rn & 7) << 4)));
#pragma unroll
        for (int mt = 0; mt < 2; ++mt) qa[mt][nt] = mfma16(a[mt], bb, qa[mt][nt]);
      }
    }
    __syncthreads();
#pragma unroll
    for (int mt = 0; mt < 2; ++mt)
#pragma unroll
      for (int nt = 0; nt < 8; ++nt) {
        int n = nt * 16 + lr;
        int c0 = w * 32 + mt * 16 + 4 * lk;
        s16x4 pk;
#pragma unroll
        for (int e = 0; e < 4; ++e) {
          float v = qa[mt][nt][e];
          pk[e] = f2bs(v > 0.f ? v : 0.f);
        }
        *(s16x4*)(qb + n * 512 + ((c0 * 2) ^ ((n & 7) << 4))) = pk;
      }
  }
  __syncthreads();
  {
    int row = t >> 2, qtr = t & 3;
    const float* kd = KVD + b * 256;
    float s = 0.f;
#pragma unroll
    for (int jj = 0; jj < 8; ++jj) {
      int chunk = qtr * 8 + jj;
      short8 v = *(const short8*)(qb + row * 512 + ((chunk * 16) ^ ((row & 7) << 4)));
      const float* kp = kd + chunk * 8;
#pragma unroll
      for (int e = 0; e < 8; ++e) s += b2f((unsigned short)v[e]) * kp[e];
    }
    s += __shfl_xor(s, 1);
    s += __shfl_xor(s, 2);
    if (qtr == 0) recip_s[row] = 1.f / (s + 1e-5f);
  }
  __syncthreads();
  f32x4 acc[8][2] = {};
  for (int k0 = 0; k0 < 256; k0 += 32) {
    short8 a[8];
#pragma unroll
    for (int mt = 0; mt < 8; ++mt) {
      int rn = mt * 16 + lr;
      a[mt] = *(const short8*)(qb + rn * 512 + ((k0 * 2 + lk * 16) ^ ((rn & 7) << 4)));
    }
#pragma unroll
    for (int nt = 0; nt < 2; ++nt) {
      short8 bw = *(const short8*)(Mb + ((size_t)b << 16) + (size_t)(w * 32 + nt * 16 + lr) * 256 + k0 + lk * 8);
#pragma unroll
      for (int mt = 0; mt < 8; ++mt) acc[mt][nt] = mfma16(a[mt], bw, acc[mt][nt]);
    }
  }
  float* Yb = Y + (size_t)b * CC * NN;
#pragma unroll
  for (int mt = 0; mt < 8; ++mt)
#pragma unroll
    for (int nt = 0; nt < 2; ++nt) {
      int o = w * 32 + nt * 16 + lr;
      int nb = mt * 16 + 4 * lk;
      f32x4 out;
#pragma unroll
      for (int e = 0; e < 4; ++e) out[e] = acc[mt][nt][e] * recip_s[nb + e] + shift_s[o];
      *(f32x4*)(Yb + (size_t)o * NN + n0 + nb) = out;
    }
}

extern "C" void kernel_launch(void* const* d_in, const int* in_sizes, int n_in,
                              void* d_out, int out_size, void* d_ws, size_t ws_size,
                              hipStream_t stream) {
  const float* x = (const float*)d_in[0];
  const float* Wqkv = (const float*)d_in[1];
  const float* Wproj = (const float*)d_in[2];
  const float* g = (const float*)d_in[3];
  const float* bta = (const float*)d_in[4];
  const float* mu = (const float*)d_in[5];
  const float* var = (const float*)d_in[6];
  float* Y = (float*)d_out;

  char* ws = (char*)d_ws;
  size_t off = 0;
  auto alloc = [&](size_t bytes) -> void* {
    void* p = ws + off;
    off += (bytes + 255) & ~(size_t)255;
    return p;
  };
  const size_t big = (size_t)BB * NN * CC * 2;  // 33.5 MB
  bf16* KB = (bf16*)alloc(big);
  bf16* VB = (bf16*)alloc(big);
  float* PART = (float*)alloc((size_t)BB * 16 * 65536 * 4);  // 16.8 MB
  bf16* KVJ = (bf16*)alloc((size_t)BB * 65536 * 2);
  bf16* Mbuf = (bf16*)alloc((size_t)BB * 65536 * 2);
  float* KVD = (float*)alloc((size_t)BB * 256 * 4);
  bf16* Wq = (bf16*)alloc(256 * 256 * 2);
  bf16* Wkv = (bf16*)alloc(512 * 256 * 2);
  bf16* Wp = (bf16*)alloc(256 * 256 * 2);
  float* bns = (float*)alloc(512 * 4);

  prep_kernel<<<1025, 256, 0, stream>>>(Wqkv, Wproj, g, bta, mu, var, Wq, Wkv, Wp, bns, KVD);

  // host-side feasibility gate for cooperative launch (capture-safe queries)
  const unsigned smemBytes = 67072;
  bool useCoop = false;
  {
    int dev = 0;
    (void)hipGetDevice(&dev);
    int coopAttr = 0;
    (void)hipDeviceGetAttribute(&coopAttr, hipDeviceAttributeCooperativeLaunch, dev);
    if (coopAttr) {
      (void)hipFuncSetAttribute((const void*)fused_kernel,
                                hipFuncAttributeMaxDynamicSharedMemorySize, (int)smemBytes);
      int maxBlocks = 0;
      hipError_t oe = hipOccupancyMaxActiveBlocksPerMultiprocessor(
          &maxBlocks, (const void*)fused_kernel, 512, smemBytes);
      if (oe == hipSuccess && maxBlocks >= 2) useCoop = true;
    }
  }

  hipError_t err = hipErrorUnknown;
  if (useCoop) {
    void* args[] = {(void*)&x, (void*)&Wq, (void*)&Wkv, (void*)&Wp, (void*)&bns,
                    (void*)&KVD, (void*)&KB, (void*)&VB, (void*)&PART,
                    (void*)&KVJ, (void*)&Mbuf, (void*)&Y};
    err = hipLaunchCooperativeKernel((void*)fused_kernel, dim3(512), dim3(512),
                                     args, smemBytes, stream);
  }
  if (!useCoop || err != hipSuccess) {
    kv_kernel<<<dim3(NN / 128, BB), 512, 0, stream>>>(x, Wkv, KB, VB, KVD);
    g2_kernel<<<dim3(4, 16, BB), 256, 0, stream>>>(KB, VB, PART);
    kvred_kernel<<<BB * 65536 / 256, 256, 0, stream>>>(PART, KVJ);
    mker_kernel<<<dim3(2, 2, BB), 256, 0, stream>>>(Wp, KVJ, bns, Mbuf);
    g5_kernel<<<dim3(NN / 128, BB), 512, 0, stream>>>(x, Wq, Mbuf, KVD, bns, Y);
  }
}